// Round 1
// 2143.488 us; speedup vs baseline: 1.2183x; 1.2183x over previous
//
#include <hip/hip_runtime.h>
#include <hip/hip_bf16.h>

// LocalAttention MI355X — round 6: MFMA GEMM core (bf16x3 split).
// r5 passed (2611 us), MfmaUtil=0 on all GEMMs (105 of 117 GFLOP on the
// fp32 VALU at ~40% of its 157 TF ceiling). This round: replace the
// 64x64 fp32 gemm_core with a 16x16x32 bf16 MFMA core using the hi/lo
// split (AH*BH + AH*BL + AL*BH, fp32 accum) -> fp32-level accuracy at
// ~3x+ the throughput. k1/k5_dense/k4/k8/k5_add all ride the new core.
// Attention kernels (k3/k6p/k7) untouched this round.
// Fragment layouts per m89/m91-verified mapping:
//   A: row=lane%16, k=8*(lane>>4)+j ; B: col=lane%16, same k ;
//   C/D: col=lane&15, row=4*(lane>>4)+reg.

typedef __hip_bfloat16 bf16;
typedef __attribute__((ext_vector_type(8))) short short8v;          // 8 bf16
typedef __attribute__((ext_vector_type(8))) unsigned short ushort8v;
typedef __attribute__((ext_vector_type(4))) float f32x4;

#define HW_TOK 12544
#define NTOK   12560
#define ATT_SCALE 0.17677669529663687f  // 1/sqrt(32)

__device__ __forceinline__ int lwin_to_tok(int wt) {
    int w = wt / 49, t = wt - w * 49;
    int wr = w >> 4, wc = w & 15;
    int r = t / 7, c = t - r * 7;
    return (wr * 7 + r) * 112 + (wc * 7 + c);
}

__device__ __forceinline__ float b2f(unsigned short u) {
    unsigned int w = ((unsigned int)u) << 16;
    return *reinterpret_cast<float*>(&w);
}
__device__ __forceinline__ unsigned short f2b(float v) {
    bf16 h = __float2bfloat16(v);
    return *reinterpret_cast<unsigned short*>(&h);
}

template<bool F32>
__device__ __forceinline__ float ldv(const void* p, size_t i) {
    if constexpr (F32) return reinterpret_cast<const float*>(p)[i];
    else return b2f(reinterpret_cast<const unsigned short*>(p)[i]);
}
template<bool F32>
__device__ __forceinline__ float4 ldv4(const void* p, size_t i) {
    if constexpr (F32) {
        return *reinterpret_cast<const float4*>(reinterpret_cast<const float*>(p) + i);
    } else {
        ushort4 u = *reinterpret_cast<const ushort4*>(
            reinterpret_cast<const unsigned short*>(p) + i);
        return float4{b2f(u.x), b2f(u.y), b2f(u.z), b2f(u.w)};
    }
}
template<bool F32>
__device__ __forceinline__ void stv(void* p, size_t i, float v) {
    if constexpr (F32) reinterpret_cast<float*>(p)[i] = v;
    else reinterpret_cast<unsigned short*>(p)[i] = f2b(v);
}
template<bool F32>
__device__ __forceinline__ void stv4(void* p, size_t i, float4 v) {
    if constexpr (F32) {
        *reinterpret_cast<float4*>(reinterpret_cast<float*>(p) + i) = v;
    } else {
        ushort4 u{f2b(v.x), f2b(v.y), f2b(v.z), f2b(v.w)};
        *reinterpret_cast<ushort4*>(reinterpret_cast<unsigned short*>(p) + i) = u;
    }
}

// ---------------- dtype probe (f32 -> flag=1, bf16 -> flag=0) ------------
__global__ void probe_dtype(const unsigned short* x, int n_elem, int* flag) {
    int tid = threadIdx.x;
    int stride = (n_elem / 2048) & ~1;
    if (stride < 2) stride = 2;
    int insane = 0;
    for (int s = 0; s < 8; ++s) {
        long idx = (long)(tid * 8 + s) * stride;
        if (idx >= n_elem) idx = idx % n_elem & ~1L;
        unsigned short u = x[idx];
        unsigned e = (u >> 7) & 0xFF;
        if (e == 0xFF || e >= 141 || (e >= 1 && e <= 112)) insane++;
    }
    __shared__ int tot;
    if (tid == 0) tot = 0;
    __syncthreads();
    atomicAdd(&tot, insane);
    __syncthreads();
    if (tid == 0) flag[0] = (tot > 512) ? 1 : 0;
}

// ---------------- MFMA helpers -------------------------------------------
__device__ __forceinline__ f32x4 mfma_bb(short8v a, short8v b, f32x4 c) {
    return __builtin_amdgcn_mfma_f32_16x16x32_bf16(a, b, c, 0, 0, 0);
}
// split-product accumulate: c += aH*bH + aH*bL + aL*bH (lo*lo dropped, ~2^-18)
__device__ __forceinline__ f32x4 mfma3(short8v aH, short8v aL,
                                       short8v bH, short8v bL, f32x4 c) {
    c = mfma_bb(aH, bH, c);
    c = mfma_bb(aH, bL, c);
    c = mfma_bb(aL, bH, c);
    return c;
}

// 8 fp32 -> 8 bf16 hi + 8 bf16 lo (exact residual split)
__device__ __forceinline__ void cvt8(float4 f0, float4 f1,
                                     ushort8v& hi, ushort8v& lo) {
    float ff[8] = {f0.x, f0.y, f0.z, f0.w, f1.x, f1.y, f1.z, f1.w};
    #pragma unroll
    for (int i = 0; i < 8; ++i) {
        unsigned short h = f2b(ff[i]);
        hi[i] = h;
        lo[i] = f2b(ff[i] - b2f(h));
    }
}

// ---------------- shared 64x64x256 MFMA SGEMM core -----------------------
// 256 threads = 4 waves in a 2x2 arrangement of 32x32 wave tiles.
// abase/bbase: element base of this thread's staging row (row = tid&63).
// LDS rows padded to 72 shorts (144 B) -> fragment ds_read_b128s spread
// evenly over all 32 banks (stride 36 dwords, period 8 rows).
template<bool F32>
__device__ __forceinline__ void gemm_core_mfma(
    const void* A, size_t abase, const void* B, size_t bbase,
    f32x4 (&acc)[2][2], int tid)
{
    __shared__ __align__(16) unsigned short AsH[64][72];
    __shared__ __align__(16) unsigned short AsL[64][72];
    __shared__ __align__(16) unsigned short BsH[64][72];
    __shared__ __align__(16) unsigned short BsL[64][72];

    const int lane = tid & 63;
    const int wave = tid >> 6;
    const int wr = (wave >> 1) * 32;   // wave tile row offset
    const int wc = (wave & 1) * 32;    // wave tile col offset
    const int fr  = lane & 15;         // fragment row/col within 16
    const int fkb = (lane >> 4) * 8;   // fragment k offset (shorts)
    const int srow = lane;             // staging row
    const int skq  = wave * 16;        // staging k offset (floats)

    for (int k0 = 0; k0 < 256; k0 += 64) {
        if (k0) __syncthreads();       // previous chunk fully consumed
        #pragma unroll
        for (int half = 0; half < 2; ++half) {
            int kf = k0 + skq + half * 8;
            float4 a0 = ldv4<F32>(A, abase + kf);
            float4 a1 = ldv4<F32>(A, abase + kf + 4);
            float4 b0 = ldv4<F32>(B, bbase + kf);
            float4 b1 = ldv4<F32>(B, bbase + kf + 4);
            ushort8v h, l;
            cvt8(a0, a1, h, l);
            *reinterpret_cast<ushort8v*>(&AsH[srow][skq + half * 8]) = h;
            *reinterpret_cast<ushort8v*>(&AsL[srow][skq + half * 8]) = l;
            cvt8(b0, b1, h, l);
            *reinterpret_cast<ushort8v*>(&BsH[srow][skq + half * 8]) = h;
            *reinterpret_cast<ushort8v*>(&BsL[srow][skq + half * 8]) = l;
        }
        __syncthreads();
        #pragma unroll
        for (int kk = 0; kk < 2; ++kk) {
            int kb = kk * 32 + fkb;
            short8v aH0 = *reinterpret_cast<const short8v*>(&AsH[wr + fr][kb]);
            short8v aL0 = *reinterpret_cast<const short8v*>(&AsL[wr + fr][kb]);
            short8v aH1 = *reinterpret_cast<const short8v*>(&AsH[wr + 16 + fr][kb]);
            short8v aL1 = *reinterpret_cast<const short8v*>(&AsL[wr + 16 + fr][kb]);
            short8v bH0 = *reinterpret_cast<const short8v*>(&BsH[wc + fr][kb]);
            short8v bL0 = *reinterpret_cast<const short8v*>(&BsL[wc + fr][kb]);
            short8v bH1 = *reinterpret_cast<const short8v*>(&BsH[wc + 16 + fr][kb]);
            short8v bL1 = *reinterpret_cast<const short8v*>(&BsL[wc + 16 + fr][kb]);
            acc[0][0] = mfma3(aH0, aL0, bH0, bL0, acc[0][0]);
            acc[0][1] = mfma3(aH0, aL0, bH1, bL1, acc[0][1]);
            acc[1][0] = mfma3(aH1, aL1, bH0, bL0, acc[1][0]);
            acc[1][1] = mfma3(aH1, aL1, bH1, bL1, acc[1][1]);
        }
    }
}

// epilogue coordinates: this lane's output frag base within the 64x64 tile
__device__ __forceinline__ void epi_coords(int tid, int& rbase, int& cbase) {
    int lane = tid & 63, wave = tid >> 6;
    rbase = (wave >> 1) * 32 + ((lane >> 4) << 2);
    cbase = (wave & 1) * 32 + (lane & 15);
}

// ---------------- K1: per-batch windowed QKV GEMM ------------------------
template<bool F32>
__device__ void k1_body(const void* x, const void* w, const void* bias,
                        void* qkvb, int b) {
    __shared__ unsigned rowsrc[64];
    int tid = threadIdx.x;
    int m0 = blockIdx.x * 64, n0 = blockIdx.y * 64;
    if (tid < 64)
        rowsrc[tid] = (unsigned)(b * NTOK + lwin_to_tok(m0 + tid)) * 256;
    __syncthreads();
    f32x4 acc[2][2] = {};
    size_t abase = rowsrc[tid & 63];
    size_t bbase = (size_t)(n0 + (tid & 63)) * 256;
    gemm_core_mfma<F32>(x, abase, w, bbase, acc, tid);
    int rbase, cbase; epi_coords(tid, rbase, cbase);
    #pragma unroll
    for (int ni = 0; ni < 2; ++ni) {
        int n = n0 + cbase + ni * 16;
        float bi = ldv<F32>(bias, n);
        #pragma unroll
        for (int mi = 0; mi < 2; ++mi)
            #pragma unroll
            for (int r = 0; r < 4; ++r)
                stv<F32>(qkvb, (size_t)(m0 + rbase + mi * 16 + r) * 768 + n,
                         acc[mi][ni][r] + bi);
    }
}
__global__ __launch_bounds__(256) void k1_qkv_win(
    const void* x, const void* w, const void* bia, void* qkvb, int b,
    const int* flag) {
    if (flag[0]) k1_body<true>(x, w, bia, qkvb, b);
    else         k1_body<false>(x, w, bia, qkvb, b);
}

// ---------------- K3: per-batch window attention + fused RoPE ------------
template<bool F32>
__device__ void k3_body(const void* qkvb, const int* pos2d, void* owin, int b) {
    int wb = blockIdx.x, h = blockIdx.y, tid = threadIdx.x;
    __shared__ __align__(16) float qs[49][32];
    __shared__ __align__(16) float ks[49][36];
    __shared__ __align__(16) float vs[49][36];
    __shared__ float S[49][52];
    for (int e = tid; e < 49 * 32; e += 256) {
        int t = e >> 5, d = e & 31;
        int n = lwin_to_tok(wb * 49 + t);
        int half = d >> 4, i = d & 7;
        int pos = pos2d[(size_t)(b * NTOK + n) * 2 + half];
        float inv = exp2f((float)i * -0.8304820237218407f);  // 100^(-i/8)
        float ang = (float)pos * inv;
        float sn, cs; sincosf(ang, &sn, &cs);
        float sgn = (d & 8) ? 1.0f : -1.0f;
        size_t base = (size_t)(wb * 49 + t) * 768 + h * 32;
        float qd = ldv<F32>(qkvb, base + d);
        float qp = ldv<F32>(qkvb, base + (d ^ 8));
        float kd = ldv<F32>(qkvb, base + 256 + d);
        float kp = ldv<F32>(qkvb, base + 256 + (d ^ 8));
        qs[t][d] = qd * cs + sgn * qp * sn;
        ks[t][d] = kd * cs + sgn * kp * sn;
        vs[t][d] = ldv<F32>(qkvb, base + 512 + d);
    }
    __syncthreads();
    for (int e = tid; e < 49 * 49; e += 256) {
        int i = e / 49, j = e - i * 49;
        float a = 0.f;
        #pragma unroll
        for (int dg = 0; dg < 8; ++dg) {
            float4 qv = *reinterpret_cast<const float4*>(&qs[i][dg * 4]);
            float4 kv = *reinterpret_cast<const float4*>(&ks[j][dg * 4]);
            a = fmaf(qv.x, kv.x, a); a = fmaf(qv.y, kv.y, a);
            a = fmaf(qv.z, kv.z, a); a = fmaf(qv.w, kv.w, a);
        }
        S[i][j] = a * ATT_SCALE;
    }
    __syncthreads();
    if (tid < 49) {
        float mx = -1e30f;
        for (int j = 0; j < 49; ++j) mx = fmaxf(mx, S[tid][j]);
        float sum = 0.f;
        for (int j = 0; j < 49; ++j) { float p = expf(S[tid][j] - mx); S[tid][j] = p; sum += p; }
        float r = 1.0f / sum;
        for (int j = 0; j < 49; ++j) S[tid][j] *= r;
    }
    __syncthreads();
    for (int e = tid; e < 49 * 8; e += 256) {
        int t = e >> 3, dg = (e & 7) * 4;
        float4 o{0.f, 0.f, 0.f, 0.f};
        for (int j = 0; j < 49; ++j) {
            float p = S[t][j];
            float4 v = *reinterpret_cast<const float4*>(&vs[j][dg]);
            o.x = fmaf(p, v.x, o.x); o.y = fmaf(p, v.y, o.y);
            o.z = fmaf(p, v.z, o.z); o.w = fmaf(p, v.w, o.w);
        }
        stv4<F32>(owin, (size_t)(wb * 49 + t) * 256 + h * 32 + dg, o);
    }
}
__global__ __launch_bounds__(256) void k3_winattn(
    const void* qkvb, const int* pos2d, void* owin, int b, const int* flag) {
    if (flag[0]) k3_body<true>(qkvb, pos2d, owin, b);
    else         k3_body<false>(qkvb, pos2d, owin, b);
}

// ---------------- K4: per-batch projection + un-partition -> out ---------
template<bool F32>
__device__ void k4_body(const void* owin, const void* w, const void* bias,
                        void* out, int b) {
    __shared__ unsigned rowdst[64];
    int tid = threadIdx.x;
    int m0 = blockIdx.x * 64, n0 = blockIdx.y * 64;
    if (tid < 64)
        rowdst[tid] = (unsigned)(b * NTOK + lwin_to_tok(m0 + tid)) * 256;
    f32x4 acc[2][2] = {};
    size_t abase = (size_t)(m0 + (tid & 63)) * 256;
    size_t bbase = (size_t)(n0 + (tid & 63)) * 256;
    gemm_core_mfma<F32>(owin, abase, w, bbase, acc, tid);
    int rbase, cbase; epi_coords(tid, rbase, cbase);
    #pragma unroll
    for (int ni = 0; ni < 2; ++ni) {
        int n = n0 + cbase + ni * 16;
        float bi = ldv<F32>(bias, n);
        #pragma unroll
        for (int mi = 0; mi < 2; ++mi)
            #pragma unroll
            for (int r = 0; r < 4; ++r)
                stv<F32>(out, (size_t)rowdst[rbase + mi * 16 + r] + n,
                         acc[mi][ni][r] + bi);
    }
}
__global__ __launch_bounds__(256) void k4_proj_win(
    const void* owin, const void* w, const void* bia, void* out, int b,
    const int* flag) {
    if (flag[0]) k4_body<true>(owin, w, bia, out, b);
    else         k4_body<false>(owin, w, bia, out, b);
}

// ---------------- K5d: per-batch dense QKV GEMM of x2 (in out) -----------
template<bool F32>
__device__ void k5d_body(const void* out, const void* w, const void* bias,
                         void* qkvb, int b) {
    int tid = threadIdx.x;
    int m0 = blockIdx.x * 64, n0 = blockIdx.y * 64;
    f32x4 acc[2][2] = {};
    size_t abase = ((size_t)b * NTOK + m0 + (tid & 63)) * 256;
    size_t bbase = (size_t)(n0 + (tid & 63)) * 256;
    gemm_core_mfma<F32>(out, abase, w, bbase, acc, tid);
    int rbase, cbase; epi_coords(tid, rbase, cbase);
    #pragma unroll
    for (int ni = 0; ni < 2; ++ni) {
        int n = n0 + cbase + ni * 16;
        float bi = ldv<F32>(bias, n);
        #pragma unroll
        for (int mi = 0; mi < 2; ++mi)
            #pragma unroll
            for (int r = 0; r < 4; ++r)
                stv<F32>(qkvb, (size_t)(m0 + rbase + mi * 16 + r) * 768 + n,
                         acc[mi][ni][r] + bi);
    }
}
__global__ __launch_bounds__(256) void k5_dense(
    const void* out, const void* w, const void* bia, void* qkvb, int b,
    const int* flag) {
    if (flag[0]) k5d_body<true>(out, w, bia, qkvb, b);
    else         k5d_body<false>(out, w, bia, qkvb, b);
}

// ---------------- K5add: qkv of 128 added tokens (f32 out) ---------------
template<bool F32>
__device__ void k5a_body(const void* x, const void* w, const void* bias,
                         float* qadd) {
    int tid = threadIdx.x;
    int m0 = blockIdx.x * 64, n0 = blockIdx.y * 64;
    int row = m0 + (tid & 63);                 // 0..127
    int bb = row >> 4, a = row & 15;
    f32x4 acc[2][2] = {};
    size_t abase = ((size_t)bb * NTOK + HW_TOK + a) * 256;
    size_t bbase = (size_t)(n0 + (tid & 63)) * 256;
    gemm_core_mfma<F32>(x, abase, w, bbase, acc, tid);
    int rbase, cbase; epi_coords(tid, rbase, cbase);
    #pragma unroll
    for (int ni = 0; ni < 2; ++ni) {
        int n = n0 + cbase + ni * 16;
        float bi = ldv<F32>(bias, n);
        #pragma unroll
        for (int mi = 0; mi < 2; ++mi)
            #pragma unroll
            for (int r = 0; r < 4; ++r)
                qadd[(size_t)(m0 + rbase + mi * 16 + r) * 768 + n] =
                    acc[mi][ni][r] + bi;
    }
}
__global__ __launch_bounds__(256) void k5_add(
    const void* x, const void* w, const void* bia, float* qadd,
    const int* flag) {
    if (flag[0]) k5a_body<true>(x, w, bia, qadd);
    else         k5a_body<false>(x, w, bia, qadd);
}

// ---------------- K6p: o_add flash partials (8h x 64s grid) --------------
template<bool F32>
__device__ void k6p_body(const float* qadd, const void* qkvb,
                         float* part, int b) {
    int h = blockIdx.x, s = blockIdx.y, tid = threadIdx.x;
    __shared__ __align__(16) float qa[16][32];
    __shared__ __align__(16) float ks[49][36];
    __shared__ __align__(16) float vs[49][36];
    __shared__ float S[16][52];
    __shared__ float mrow[16], lrow[16], crow[16];
    int aq = tid >> 3, adg = (tid & 7) * 4;    // valid for tid<128
    if (tid < 128)
        *reinterpret_cast<float4*>(&qa[aq][adg]) =
            *reinterpret_cast<const float4*>(
                &qadd[(size_t)(b * 16 + aq) * 768 + h * 32 + adg]);
    if (tid < 16) { mrow[tid] = -1e30f; lrow[tid] = 0.f; }
    float4 acc{0.f, 0.f, 0.f, 0.f};
    __syncthreads();
    for (int c = 0; c < 4; ++c) {
        int row0 = s * 196 + c * 49;
        for (int e = tid; e < 49 * 8; e += 256) {
            int j = e >> 3, dg = (e & 7) * 4;
            size_t base = (size_t)(row0 + j) * 768 + 256 + h * 32 + dg;
            *reinterpret_cast<float4*>(&ks[j][dg]) = ldv4<F32>(qkvb, base);
            *reinterpret_cast<float4*>(&vs[j][dg]) = ldv4<F32>(qkvb, base + 256);
        }
        __syncthreads();
        for (int e = tid; e < 784; e += 256) {
            int q = e / 49, j = e - q * 49;
            float a = 0.f;
            #pragma unroll
            for (int dg = 0; dg < 8; ++dg) {
                float4 qv = *reinterpret_cast<const float4*>(&qa[q][dg * 4]);
                float4 kv = *reinterpret_cast<const float4*>(&ks[j][dg * 4]);
                a = fmaf(qv.x, kv.x, a); a = fmaf(qv.y, kv.y, a);
                a = fmaf(qv.z, kv.z, a); a = fmaf(qv.w, kv.w, a);
            }
            S[q][j] = a * ATT_SCALE;
        }
        __syncthreads();
        if (tid < 16) {
            float m = mrow[tid], sm = m;
            for (int j = 0; j < 49; ++j) sm = fmaxf(sm, S[tid][j]);
            float corr = expf(m - sm);
            float l = lrow[tid] * corr;
            for (int j = 0; j < 49; ++j) { float p = expf(S[tid][j] - sm); S[tid][j] = p; l += p; }
            mrow[tid] = sm; lrow[tid] = l; crow[tid] = corr;
        }
        __syncthreads();
        if (tid < 128) {
            float cr = crow[aq];
            acc.x *= cr; acc.y *= cr; acc.z *= cr; acc.w *= cr;
            for (int j = 0; j < 49; ++j) {
                float p = S[aq][j];
                float4 v = *reinterpret_cast<const float4*>(&vs[j][adg]);
                acc.x = fmaf(p, v.x, acc.x); acc.y = fmaf(p, v.y, acc.y);
                acc.z = fmaf(p, v.z, acc.z); acc.w = fmaf(p, v.w, acc.w);
            }
        }
        __syncthreads();
    }
    size_t pb = (size_t)(h * 64 + s) * 544;
    if (tid < 128)
        *reinterpret_cast<float4*>(&part[pb + tid * 4]) = acc;
    if (tid < 16) { part[pb + 512 + tid] = mrow[tid]; part[pb + 528 + tid] = lrow[tid]; }
}
__global__ __launch_bounds__(256) void k6_oadd_part(
    const float* qadd, const void* qkvb, float* part, int b, const int* flag) {
    if (flag[0]) k6p_body<true>(qadd, qkvb, part, b);
    else         k6p_body<false>(qadd, qkvb, part, b);
}

// ---------------- K6m: merge 64 o_add partials per head ------------------
__global__ __launch_bounds__(256) void k6_merge(
    const float* __restrict__ part, float* __restrict__ oadd, int b)
{
    int h = blockIdx.x, tid = threadIdx.x;
    if (tid >= 128) return;
    int q = tid >> 3, dg = (tid & 7) * 4;
    float M = -1e30f;
    for (int s2 = 0; s2 < 64; ++s2)
        M = fmaxf(M, part[(size_t)(h * 64 + s2) * 544 + 512 + q]);
    float4 o{0.f, 0.f, 0.f, 0.f};
    float L = 0.f;
    for (int s2 = 0; s2 < 64; ++s2) {
        size_t pb = (size_t)(h * 64 + s2) * 544;
        float w = expf(part[pb + 512 + q] - M);
        float4 pv = *reinterpret_cast<const float4*>(&part[pb + q * 32 + dg]);
        o.x = fmaf(w, pv.x, o.x); o.y = fmaf(w, pv.y, o.y);
        o.z = fmaf(w, pv.z, o.z); o.w = fmaf(w, pv.w, o.w);
        L = fmaf(w, part[pb + 528 + q], L);
    }
    float r = 1.f / L;
    float4 res{o.x * r, o.y * r, o.z * r, o.w * r};
    *reinterpret_cast<float4*>(&oadd[(size_t)(b * 16 + q) * 256 + h * 32 + dg]) = res;
}

// ---------------- K6b: projection of o_add -> out added rows -------------
template<bool F32>
__device__ void k6b_body(const float* oadd, const void* proj_w,
                         const void* proj_bias, void* out) {
    int row = blockIdx.x;   // b*16 + a
    int tid = threadIdx.x;
    __shared__ __align__(16) float o[256];
    o[tid] = oadd[(size_t)row * 256 + tid];
    __syncthreads();
    float acc = ldv<F32>(proj_bias, tid);
    #pragma unroll 4
    for (int kg = 0; kg < 64; ++kg) {
        float4 w4 = ldv4<F32>(proj_w, (size_t)tid * 256 + kg * 4);
        float4 o4 = *reinterpret_cast<const float4*>(&o[kg * 4]);
        acc = fmaf(o4.x, w4.x, acc); acc = fmaf(o4.y, w4.y, acc);
        acc = fmaf(o4.z, w4.z, acc); acc = fmaf(o4.w, w4.w, acc);
    }
    int b = row >> 4, a = row & 15;
    stv<F32>(out, ((size_t)b * NTOK + HW_TOK + a) * 256 + tid, acc);
}
__global__ __launch_bounds__(256) void k6b_oadd_proj(
    const float* oadd, const void* w, const void* bia, void* out,
    const int* flag) {
    if (flag[0]) k6b_body<true>(oadd, w, bia, out);
    else         k6b_body<false>(oadd, w, bia, out);
}

// ---------------- K7: per-batch spatial->added attention (upd) -----------
template<bool F32>
__device__ void k7_body(const float* qadd, const void* qkvb, void* updb, int b) {
    int tid = threadIdx.x;
    int n0 = blockIdx.x * 32;
    __shared__ __align__(16) float ka[8][16][32];
    __shared__ __align__(16) float va[8][16][32];
    float* kaf = &ka[0][0][0];
    float* vaf = &va[0][0][0];
    for (int e = tid; e < 1024; e += 256) {
        int g = e * 4;
        int h2 = g >> 9, rem = g & 511, a = rem >> 5, d = rem & 31;
        size_t base = (size_t)(b * 16 + a) * 768 + 256 + h2 * 32 + d;
        *reinterpret_cast<float4*>(&kaf[g]) =
            *reinterpret_cast<const float4*>(&qadd[base]);
        *reinterpret_cast<float4*>(&vaf[g]) =
            *reinterpret_cast<const float4*>(&qadd[base + 256]);
    }
    __syncthreads();
    int tok = tid & 31, h = tid >> 5;
    int rowl = n0 + tok;
    float q[32];
    #pragma unroll
    for (int dg = 0; dg < 8; ++dg) {
        float4 q4 = ldv4<F32>(qkvb, (size_t)rowl * 768 + h * 32 + dg * 4);
        q[dg * 4 + 0] = q4.x; q[dg * 4 + 1] = q4.y;
        q[dg * 4 + 2] = q4.z; q[dg * 4 + 3] = q4.w;
    }
    float s[16];
    float mx = -1e30f;
    #pragma unroll
    for (int a = 0; a < 16; ++a) {
        float acc = 0.f;
        #pragma unroll
        for (int d = 0; d < 32; ++d) acc = fmaf(q[d], ka[h][a][d], acc);
        s[a] = acc * ATT_SCALE; mx = fmaxf(mx, s[a]);
    }
    float sum = 0.f;
    #pragma unroll
    for (int a = 0; a < 16; ++a) { s[a] = expf(s[a] - mx); sum += s[a]; }
    float r = 1.0f / sum;
    #pragma unroll
    for (int a = 0; a < 16; ++a) s[a] *= r;
    #pragma unroll
    for (int dg = 0; dg < 8; ++dg) {
        float4 o{0.f, 0.f, 0.f, 0.f};
        #pragma unroll
        for (int a = 0; a < 16; ++a) {
            float p = s[a];
            o.x = fmaf(p, va[h][a][dg * 4 + 0], o.x);
            o.y = fmaf(p, va[h][a][dg * 4 + 1], o.y);
            o.z = fmaf(p, va[h][a][dg * 4 + 2], o.z);
            o.w = fmaf(p, va[h][a][dg * 4 + 3], o.w);
        }
        stv4<F32>(updb, (size_t)rowl * 256 + h * 32 + dg * 4, o);
    }
}
__global__ __launch_bounds__(256) void k7_upd(
    const float* qadd, const void* qkvb, void* updb, int b, const int* flag) {
    if (flag[0]) k7_body<true>(qadd, qkvb, updb, b);
    else         k7_body<false>(qadd, qkvb, updb, b);
}

// ---------------- K8: per-batch final proj, out += 0.5*proj(upd) ---------
template<bool F32>
__device__ void k8_body(const void* updb, const void* w, const void* bias,
                        void* out, int b) {
    int tid = threadIdx.x;
    int m0 = blockIdx.x * 64, n0 = blockIdx.y * 64;
    f32x4 acc[2][2] = {};
    size_t abase = (size_t)(m0 + (tid & 63)) * 256;
    size_t bbase = (size_t)(n0 + (tid & 63)) * 256;
    gemm_core_mfma<F32>(updb, abase, w, bbase, acc, tid);
    int rbase, cbase; epi_coords(tid, rbase, cbase);
    #pragma unroll
    for (int ni = 0; ni < 2; ++ni) {
        int n = n0 + cbase + ni * 16;
        float bi = ldv<F32>(bias, n);
        #pragma unroll
        for (int mi = 0; mi < 2; ++mi)
            #pragma unroll
            for (int r = 0; r < 4; ++r) {
                size_t obase = ((size_t)b * NTOK + m0 + rbase + mi * 16 + r) * 256 + n;
                float xv = ldv<F32>(out, obase);
                stv<F32>(out, obase, xv + 0.5f * (acc[mi][ni][r] + bi));
            }
    }
}
__global__ __launch_bounds__(256) void k8_final(
    const void* updb, const void* w, const void* bia, void* out, int b,
    const int* flag) {
    if (flag[0]) k8_body<true>(updb, w, bia, out, b);
    else         k8_body<false>(updb, w, bia, out, b);
}

extern "C" void kernel_launch(void* const* d_in, const int* in_sizes, int n_in,
                              void* d_out, int out_size, void* d_ws, size_t ws_size,
                              hipStream_t stream) {
    const void* x      = d_in[0];
    const int*  pos2d  = (const int*)d_in[1];
    // d_in[2] = rope_mask: all-true — unused.
    const void* qkv_w  = d_in[3];
    const void* qkv_b  = d_in[4];
    const void* proj_w = d_in[5];
    const void* proj_b = d_in[6];
    void* out = d_out;

    // ws layout (bytes), max end 52,183,044 — identical bound to r5 (proven).
    char* wsb = (char*)d_ws;
    void*  qkvb = (void*)wsb;                 // <= 12544*768*4 = 38,535,168 B
    void*  owin = (void*)(wsb + 38535168);    // <= 12544*256*4 = 12,845,056 B
    void*  updb = owin;
    float* part = (float*)(wsb + 38535168);   // 8*64*544*4 = 1,114,112 B (overlap)
    float* qadd = (float*)(wsb + 51380224);   // 128*768*4 = 393,216 B
    float* oadd = (float*)(wsb + 52051968);   // 128*256*4 = 131,072 B
    int*   flag = (int*)(wsb + 52183040);     // 4 B
    (void)ws_size; (void)n_in; (void)out_size;

    probe_dtype<<<dim3(1), 256, 0, stream>>>((const unsigned short*)x,
                                             in_sizes[0], flag);
    k5_add<<<dim3(2, 12), 256, 0, stream>>>(x, qkv_w, qkv_b, qadd, flag);

    for (int b = 0; b < 8; ++b) {
        k1_qkv_win  <<<dim3(196, 12), 256, 0, stream>>>(x, qkv_w, qkv_b, qkvb, b, flag);
        k3_winattn  <<<dim3(256, 8),  256, 0, stream>>>(qkvb, pos2d, owin, b, flag);
        k4_proj_win <<<dim3(196, 4),  256, 0, stream>>>(owin, proj_w, proj_b, out, b, flag);
        k5_dense    <<<dim3(196, 12), 256, 0, stream>>>(out, qkv_w, qkv_b, qkvb, b, flag);
        k6_oadd_part<<<dim3(8, 64),   256, 0, stream>>>(qadd, qkvb, part, b, flag);
        k6_merge    <<<dim3(8),       256, 0, stream>>>(part, oadd, b);
        k7_upd      <<<dim3(392),     256, 0, stream>>>(qadd, qkvb, updb, b, flag);
        k8_final    <<<dim3(196, 4),  256, 0, stream>>>(updb, proj_w, proj_b, out, b, flag);
    }
    k6b_oadd_proj<<<dim3(128), 256, 0, stream>>>(oadd, proj_w, proj_b, out, flag);
}